// Round 15
// baseline (593.413 us; speedup 1.0000x reference)
//
#include <hip/hip_runtime.h>

#define CN 256
#define HN 64
#define WN 64
#define NNW 32
#define HW (HN*WN)            // 4096
#define NREF (NNW*HW)         // 131072
#define KD 256

#define BMT 256               // block M tile (wave owns 64 rows)
#define BNT 64                // B rows per window (32 KB, full K)
#define NCHV 32               // n-chunks; grid = 16 bm x 32 nch = 512 = 2/CU
#define NTILES (NREF/NCHV/BNT) // 64

using bf16x8 = __attribute__((ext_vector_type(8))) short;
using f32x16 = __attribute__((ext_vector_type(16))) float;

__device__ inline unsigned short f2bf(float x) {
  unsigned int u = __float_as_uint(x);
  return (unsigned short)((u + 0x7fffu + ((u >> 16) & 1u)) >> 16);
}

__device__ inline void atomicMaxFloat(float* addr, float val) {
  if (val >= 0.f) atomicMax(reinterpret_cast<int*>(addr), __float_as_int(val));
  else            atomicMin(reinterpret_cast<unsigned int*>(addr), __float_as_uint(val));
}

__device__ inline void gload_lds16(const void* g, void* l) {
  __builtin_amdgcn_global_load_lds(
      (const __attribute__((address_space(1))) void*)g,
      (__attribute__((address_space(3))) void*)l, 16, 0, 0);
}

// ---------------- normalize (refs blocks 0..2047, img blocks 2048..2111) ----
__global__ __launch_bounds__(256)
void norm_kernel(const float* __restrict__ refs, const float* __restrict__ img,
                 unsigned short* __restrict__ Rb, unsigned short* __restrict__ Qb,
                 float* __restrict__ out) {
  __shared__ float tile[CN][WN + 1];
  __shared__ float ssq[4][WN];
  __shared__ float scl[WN];
  const int bid = blockIdx.x;
  const int t = threadIdx.x;
  const float* src; unsigned short* dst; int nh;
  if (bid < NNW * HN) { src = refs; dst = Rb; nh = bid; }
  else {
    src = img; dst = Qb; nh = bid - NNW * HN;
    if (t < 64) out[(size_t)nh * 64 + t] = -INFINITY;   // init output
  }
  const float* base = src + (size_t)(nh >> 6) * (CN * (size_t)HW) + (size_t)(nh & 63) * WN;

  const int c16 = t >> 4, w4 = (t & 15) * 4;
#pragma unroll
  for (int j = 0; j < 16; ++j) {
    int c = j * 16 + c16;
    float4 v = *(const float4*)&base[(size_t)c * HW + w4];
    tile[c][w4 + 0] = v.x; tile[c][w4 + 1] = v.y;
    tile[c][w4 + 2] = v.z; tile[c][w4 + 3] = v.w;
  }
  __syncthreads();
  {
    int w = t & 63, vv = t >> 6;
    float s = 0.f;
#pragma unroll 8
    for (int cc = 0; cc < 64; ++cc) { float x = tile[vv * 64 + cc][w]; s += x * x; }
    ssq[vv][w] = s;
  }
  __syncthreads();
  if (t < 64)
    scl[t] = 1.f / fmaxf(sqrtf(ssq[0][t] + ssq[1][t] + ssq[2][t] + ssq[3][t]), 1e-12f);
  __syncthreads();
  const int w = t >> 2, cq = t & 3;
  unsigned short* orow = dst + ((size_t)nh * WN + w) * KD;
  const float sc = scl[w];
#pragma unroll
  for (int j = 0; j < 8; ++j) {
    int c0 = (j * 4 + cq) * 8;
    bf16x8 o;
#pragma unroll
    for (int k = 0; k < 8; ++k) o[k] = (short)f2bf(tile[c0 + k][w] * sc);
    *(bf16x8*)&orow[c0] = o;
  }
}

// -- GEMM-max: 32x32x16 MFMA, full-K 512B rows, phys chunk = c ^ (row&31) ----
#define BARR() __builtin_amdgcn_s_barrier()
#define SCHED0() __builtin_amdgcn_sched_barrier(0)
#define GATE(N) asm volatile("s_waitcnt vmcnt(" #N ")" ::: "memory")
#define LGKM0() asm volatile("s_waitcnt lgkmcnt(0)" ::: "memory")

// stage one window (64 rows x 256 k = 32KB) into buf P: 8 gloads/thread,
// gload q writes rows wid*16 + q*2 .. +2 (1 KB each)
#define STGW(P, BT) do { \
  _Pragma("unroll") \
  for (int q = 0; q < 8; ++q) \
    gload_lds16(rsb + (size_t)((BT) * 64 + rowq[q]) * 256 + scq[q], \
                &lds[P][(wid * 16 + q * 2) * 256]); \
} while (0)

// one half-K pass over ni-strip NI: 8 b128 reads + 16 MFMA into ac0/ac1
#define HALFK(P, NI, H, ACM) do { \
  bf16x8 bb[8]; \
  _Pragma("unroll") \
  for (int kf = 0; kf < 8; ++kf) \
    bb[kf] = *(const bf16x8*)&lds[P][((NI) * 32 + l31) * 256 \
        + (((((H) * 8 + kf) * 2 + hi) ^ l31) * 8)]; \
  __builtin_amdgcn_s_setprio(1); \
  _Pragma("unroll") \
  for (int kf = 0; kf < 8; ++kf) { \
    ac0 = __builtin_amdgcn_mfma_f32_32x32x16_bf16(a[0][(H) * 8 + kf], bb[kf], \
              ((ACM) || kf) ? ac0 : ZZ, 0, 0, 0); \
    ac1 = __builtin_amdgcn_mfma_f32_32x32x16_bf16(a[1][(H) * 8 + kf], bb[kf], \
              ((ACM) || kf) ? ac1 : ZZ, 0, 0, 0); \
  } \
  __builtin_amdgcn_s_setprio(0); \
} while (0)

// one window: 2 ni-strips x full K; fold per strip (ac stays register-light)
#define WINDOW(P) do { \
  f32x16 ac0, ac1; \
  HALFK(P, 0, 0, 0); HALFK(P, 0, 1, 1); \
  _Pragma("unroll") \
  for (int e = 0; e < 16; ++e) { run0[e] = fmaxf(run0[e], ac0[e]); \
                                 run1[e] = fmaxf(run1[e], ac1[e]); } \
  HALFK(P, 1, 0, 0); HALFK(P, 1, 1, 1); \
  _Pragma("unroll") \
  for (int e = 0; e < 16; ++e) { run0[e] = fmaxf(run0[e], ac0[e]); \
                                 run1[e] = fmaxf(run1[e], ac1[e]); } \
} while (0)

__global__ __launch_bounds__(256, 2)
void simmax_kernel(const unsigned short* __restrict__ Q,
                   const unsigned short* __restrict__ R,
                   float* __restrict__ out) {
  // 2 bufs x [64 rows][256 k] bf16 (512B rows, 32 chunks). 64 KB -> 2 blocks/CU.
  __shared__ unsigned short lds[2][16384];

  const int t = threadIdx.x;
  const int lane = t & 63;
  const int wid = t >> 6;       // 0..3 (owns M rows [wid*64, wid*64+64))
  const int hi  = lane >> 5;    // 0/1
  const int l31 = lane & 31;

  // bijective XCD swizzle: XCD x hosts wg [x*64, x*64+64)
  const int wg  = (blockIdx.x & 7) * 64 + (blockIdx.x >> 3);
  const int nch = wg >> 4;      // 0..31
  const int bm  = wg & 15;      // 0..15

  // staging geometry: gload q covers rows wid*16+q*2+{0,1}; lane l writes
  // phys chunk l31 of row +hi; source logical chunk = l31 ^ (row & 31)
  int rowq[8], scq[8];
#pragma unroll
  for (int q = 0; q < 8; ++q) {
    rowq[q] = wid * 16 + q * 2 + hi;
    scq[q] = (l31 ^ (rowq[q] & 31)) * 8;
  }
  const unsigned short* rsb = R + (size_t)nch * 4096 * 256;

  const f32x16 ZZ = {0,0,0,0,0,0,0,0,0,0,0,0,0,0,0,0};
  f32x16 run0, run1;
#pragma unroll
  for (int e = 0; e < 16; ++e) { run0[e] = -1e30f; run1[e] = -1e30f; }

  // ---- A prologue: 256 rows x 256 k in 2 passes of 128 rows (both bufs)
  bf16x8 a[2][16];              // resident A: 2 m-frags(32 rows) x 16 k-frags
#pragma unroll
  for (int p = 0; p < 2; ++p) {
#pragma unroll
    for (int b = 0; b < 2; ++b) {
      const unsigned short* qs = Q + (size_t)(bm * BMT + p * 128 + b * 64) * 256;
#pragma unroll
      for (int q = 0; q < 8; ++q)
        gload_lds16(qs + (size_t)rowq[q] * 256 + scq[q],
                    &lds[b][(wid * 16 + q * 2) * 256]);
    }
    GATE(0); BARR(); SCHED0();
    if ((wid >> 1) == p) {      // waves whose 64 M-rows live in this pass
      const int b = wid & 1;
#pragma unroll
      for (int mi = 0; mi < 2; ++mi)
#pragma unroll
        for (int kf = 0; kf < 16; ++kf)
          a[mi][kf] = *(const bf16x8*)&lds[b][(mi * 32 + l31) * 256
              + (((kf * 2 + hi) ^ l31) * 8)];
    }
    LGKM0(); BARR();            // reads done before next pass / B overwrites
  }

  // ---- B windows: dbuf; stage next, GATE(8), BARR, window, BARR
  STGW(0, 0);
  for (int bt = 0; bt < NTILES - 1; ++bt) {
    STGW((bt + 1) & 1, bt + 1);
    GATE(8); BARR(); SCHED0();
    WINDOW(bt & 1);
    BARR();
  }
  GATE(0); BARR(); SCHED0();
  WINDOW((NTILES - 1) & 1);

  // reduce over the 32 column-lanes (refs), one atomic per output M row
#pragma unroll
  for (int mi = 0; mi < 2; ++mi)
#pragma unroll
    for (int e = 0; e < 16; ++e) {
      float v = mi ? run1[e] : run0[e];
      v = fmaxf(v, __shfl_xor(v, 1));
      v = fmaxf(v, __shfl_xor(v, 2));
      v = fmaxf(v, __shfl_xor(v, 4));
      v = fmaxf(v, __shfl_xor(v, 8));
      v = fmaxf(v, __shfl_xor(v, 16));
      if (l31 == 0) {
        // 32x32 C/D: M row = (e&3) + 8*(e>>2) + 4*hi  (r8-verified)
        int row = bm * BMT + wid * 64 + mi * 32 + (e & 3) + 8 * (e >> 2) + 4 * hi;
        atomicMaxFloat(&out[row], v);
      }
    }
}

extern "C" void kernel_launch(void* const* d_in, const int* in_sizes, int n_in,
                              void* d_out, int out_size, void* d_ws, size_t ws_size,
                              hipStream_t stream) {
  const float* refs = (const float*)d_in[0];
  const float* img  = (const float*)d_in[1];
  float* out = (float*)d_out;

  unsigned short* Rb = (unsigned short*)d_ws;                 // 131072*256 bf16 = 64MB
  unsigned short* Qb = Rb + (size_t)NREF * KD;                // 4096*256 bf16 = 2MB

  hipLaunchKernelGGL(norm_kernel, dim3(NNW * HN + HN), dim3(256), 0, stream,
                     refs, img, Rb, Qb, out);
  hipLaunchKernelGGL(simmax_kernel, dim3(NCHV * (HW / BMT)), dim3(256), 0, stream,
                     Qb, Rb, out);
}

// Round 16
// 215.345 us; speedup vs baseline: 2.7556x; 2.7556x over previous
//
#include <hip/hip_runtime.h>

#define CN 256
#define HN 64
#define WN 64
#define NNW 32
#define HW (HN*WN)            // 4096
#define NREF (NNW*HW)         // 131072
#define KD 256

#define BMT 256               // block M tile (wave owns 64 rows)
#define BNT 64                // B rows per tile (32 KB, full K)
#define NCHV 32               // n-chunks; grid = 16 bm x 32 nch = 512 = 2/CU
#define NTILES (NREF/NCHV/BNT) // 64

using bf16x8 = __attribute__((ext_vector_type(8))) short;
using f32x4  = __attribute__((ext_vector_type(4))) float;

__device__ inline unsigned short f2bf(float x) {
  unsigned int u = __float_as_uint(x);
  return (unsigned short)((u + 0x7fffu + ((u >> 16) & 1u)) >> 16);
}

__device__ inline void atomicMaxFloat(float* addr, float val) {
  if (val >= 0.f) atomicMax(reinterpret_cast<int*>(addr), __float_as_int(val));
  else            atomicMin(reinterpret_cast<unsigned int*>(addr), __float_as_uint(val));
}

__device__ inline void gload_lds16(const void* g, void* l) {
  __builtin_amdgcn_global_load_lds(
      (const __attribute__((address_space(1))) void*)g,
      (__attribute__((address_space(3))) void*)l, 16, 0, 0);
}

// ---------------- normalize (refs blocks 0..2047, img blocks 2048..2111) ----
__global__ __launch_bounds__(256)
void norm_kernel(const float* __restrict__ refs, const float* __restrict__ img,
                 unsigned short* __restrict__ Rb, unsigned short* __restrict__ Qb,
                 float* __restrict__ out) {
  __shared__ float tile[CN][WN + 1];
  __shared__ float ssq[4][WN];
  __shared__ float scl[WN];
  const int bid = blockIdx.x;
  const int t = threadIdx.x;
  const float* src; unsigned short* dst; int nh;
  if (bid < NNW * HN) { src = refs; dst = Rb; nh = bid; }
  else {
    src = img; dst = Qb; nh = bid - NNW * HN;
    if (t < 64) out[(size_t)nh * 64 + t] = -INFINITY;   // init output
  }
  const float* base = src + (size_t)(nh >> 6) * (CN * (size_t)HW) + (size_t)(nh & 63) * WN;

  const int c16 = t >> 4, w4 = (t & 15) * 4;
#pragma unroll
  for (int j = 0; j < 16; ++j) {
    int c = j * 16 + c16;
    float4 v = *(const float4*)&base[(size_t)c * HW + w4];
    tile[c][w4 + 0] = v.x; tile[c][w4 + 1] = v.y;
    tile[c][w4 + 2] = v.z; tile[c][w4 + 3] = v.w;
  }
  __syncthreads();
  {
    int w = t & 63, vv = t >> 6;
    float s = 0.f;
#pragma unroll 8
    for (int cc = 0; cc < 64; ++cc) { float x = tile[vv * 64 + cc][w]; s += x * x; }
    ssq[vv][w] = s;
  }
  __syncthreads();
  if (t < 64)
    scl[t] = 1.f / fmaxf(sqrtf(ssq[0][t] + ssq[1][t] + ssq[2][t] + ssq[3][t]), 1e-12f);
  __syncthreads();
  const int w = t >> 2, cq = t & 3;
  unsigned short* orow = dst + ((size_t)nh * WN + w) * KD;
  const float sc = scl[w];
#pragma unroll
  for (int j = 0; j < 8; ++j) {
    int c0 = (j * 4 + cq) * 8;
    bf16x8 o;
#pragma unroll
    for (int k = 0; k < 8; ++k) o[k] = (short)f2bf(tile[c0 + k][w] * sc);
    *(bf16x8*)&orow[c0] = o;
  }
}

// -- GEMM-max: 4 waves x 64 M-rows in regs, dbuf B tiles, bb-pipelined strips
#define BARR() __builtin_amdgcn_s_barrier()
#define SCHED0() __builtin_amdgcn_sched_barrier(0)
#define GATE(N) asm volatile("s_waitcnt vmcnt(" #N ")" ::: "memory")
#define LGKM0() asm volatile("s_waitcnt lgkmcnt(0)" ::: "memory")

// stage one B tile (64 rows x 256 k = 32KB) into buf P: wave wid stages
// k-quarter wid; 8 gloads/thread, gload q covers rows q*8..q*8+8
#define STGB(P, BT) do { \
  _Pragma("unroll") \
  for (int q = 0; q < 8; ++q) \
    gload_lds16(rsb + (BT) * 16384 + q * 2048, &lds[P][wid * 4096 + q * 512]); \
} while (0)

// read the 8 B-fragments of ni-strip NI into register set BB
#define RDB(P, NI, BB) do { \
  _Pragma("unroll") \
  for (int kf = 0; kf < 8; ++kf) \
    BB[kf] = *(const bf16x8*)&lds[P][(kf >> 1) * 4096 + ((NI) * 16 + l15) * 64 \
        + ((((kf & 1) * 4 + (lane >> 4)) ^ l7) * 8)]; \
} while (0)

// 32-MFMA chain on fragment set BB (4 m-frags), fold into run
#define MF4(BB) do { \
  f32x4 ac0, ac1, ac2, ac3; \
  __builtin_amdgcn_s_setprio(1); \
  _Pragma("unroll") \
  for (int kf = 0; kf < 8; ++kf) { \
    ac0 = __builtin_amdgcn_mfma_f32_16x16x32_bf16(a[0][kf], BB[kf], kf ? ac0 : ZZ, 0, 0, 0); \
    ac1 = __builtin_amdgcn_mfma_f32_16x16x32_bf16(a[1][kf], BB[kf], kf ? ac1 : ZZ, 0, 0, 0); \
    ac2 = __builtin_amdgcn_mfma_f32_16x16x32_bf16(a[2][kf], BB[kf], kf ? ac2 : ZZ, 0, 0, 0); \
    ac3 = __builtin_amdgcn_mfma_f32_16x16x32_bf16(a[3][kf], BB[kf], kf ? ac3 : ZZ, 0, 0, 0); \
  } \
  __builtin_amdgcn_s_setprio(0); \
  _Pragma("unroll") \
  for (int ee = 0; ee < 4; ++ee) { \
    run[0][ee] = fmaxf(run[0][ee], ac0[ee]); \
    run[1][ee] = fmaxf(run[1][ee], ac1[ee]); \
    run[2][ee] = fmaxf(run[2][ee], ac2[ee]); \
    run[3][ee] = fmaxf(run[3][ee], ac3[ee]); \
  } \
} while (0)

// one tile: bbA/bbB double-buffered strips -> next strip's reads overlap MFMA
#define TILE(P) do { \
  RDB(P, 0, bbA); \
  RDB(P, 1, bbB); MF4(bbA); \
  RDB(P, 2, bbA); MF4(bbB); \
  RDB(P, 3, bbB); MF4(bbA); \
  MF4(bbB); \
} while (0)

__global__ __launch_bounds__(256, 2)
void simmax_kernel(const unsigned short* __restrict__ Q,
                   const unsigned short* __restrict__ R,
                   float* __restrict__ out) {
  // 2 bufs x 4 subs of [64 rows][64 k] bf16 (8 KB each). 64 KB -> 2 blocks/CU.
  __shared__ unsigned short lds[2][16384];

  const int t = threadIdx.x;
  const int lane = t & 63;
  const int wid = t >> 6;       // 0..3 (owns M rows [wid*64, wid*64+64))
  const int l15 = lane & 15;
  const int l7  = lane & 7;

  // bijective XCD swizzle: XCD x hosts wg [x*64, x*64+64)
  const int wg  = (blockIdx.x & 7) * 64 + (blockIdx.x >> 3);
  const int nch = wg >> 4;      // 0..31
  const int bm  = wg & 15;      // 0..15

  // staging: row-in-8 = lane>>3, phys chunk lane&7, src chunk = (lane&7)^(lane>>3)
  const int srow = lane >> 3;
  const int schunk = (lane & 7) ^ srow;
  // B source for wave wid (k-quarter wid), tile-row srow
  const unsigned short* rsb = R + ((size_t)nch * 4096 + srow) * KD + wid * 64 + schunk * 8;

  const f32x4 ZZ = {0.f, 0.f, 0.f, 0.f};
  f32x4 run[4];
#pragma unroll
  for (int mi = 0; mi < 4; ++mi)
#pragma unroll
    for (int ee = 0; ee < 4; ++ee) run[mi][ee] = -1e30f;

  // ---- A prologue: 256 rows x 256 k in 2 passes of 128 rows (64 KB each)
  bf16x8 a[4][8];               // resident A: 4 m-frags x 8 k-frags = 128 VGPR
#pragma unroll
  for (int p = 0; p < 2; ++p) {
#pragma unroll
    for (int b = 0; b < 2; ++b) {
      const unsigned short* qsb = Q + (size_t)(bm * BMT + p * 128 + b * 64 + srow) * KD
                                    + wid * 64 + schunk * 8;
#pragma unroll
      for (int q = 0; q < 8; ++q)
        gload_lds16(qsb + q * 2048, &lds[b][wid * 4096 + q * 512]);
    }
    GATE(0); BARR(); SCHED0();
    if ((wid >> 1) == p) {      // waves whose 64 M-rows live in this pass
      const int b = wid & 1;
#pragma unroll
      for (int mi = 0; mi < 4; ++mi)
#pragma unroll
        for (int kf = 0; kf < 8; ++kf)
          a[mi][kf] = *(const bf16x8*)&lds[b][(kf >> 1) * 4096 + (mi * 16 + l15) * 64
              + ((((kf & 1) * 4 + (lane >> 4)) ^ l7) * 8)];
    }
    LGKM0(); BARR();            // reads done before next pass / B overwrites
  }

  bf16x8 bbA[8], bbB[8];        // double-buffered B fragment sets

  // ---- B tiles: dbuf; stage next, GATE(8), BARR, pipelined strips, BARR
  STGB(0, 0);
  for (int bt = 0; bt < NTILES - 1; ++bt) {
    STGB((bt + 1) & 1, bt + 1);
    GATE(8); BARR(); SCHED0();
    TILE(bt & 1);
    BARR();
  }
  GATE(0); BARR(); SCHED0();
  TILE((NTILES - 1) & 1);

  // reduce over the 16 column-lanes, one atomic per output row
#pragma unroll
  for (int mi = 0; mi < 4; ++mi)
#pragma unroll
    for (int ee = 0; ee < 4; ++ee) {
      float v = run[mi][ee];
      v = fmaxf(v, __shfl_xor(v, 1));
      v = fmaxf(v, __shfl_xor(v, 2));
      v = fmaxf(v, __shfl_xor(v, 4));
      v = fmaxf(v, __shfl_xor(v, 8));
      if (l15 == 0)
        atomicMaxFloat(&out[bm * BMT + wid * 64 + mi * 16 + (lane >> 4) * 4 + ee], v);
    }
}

extern "C" void kernel_launch(void* const* d_in, const int* in_sizes, int n_in,
                              void* d_out, int out_size, void* d_ws, size_t ws_size,
                              hipStream_t stream) {
  const float* refs = (const float*)d_in[0];
  const float* img  = (const float*)d_in[1];
  float* out = (float*)d_out;

  unsigned short* Rb = (unsigned short*)d_ws;                 // 131072*256 bf16 = 64MB
  unsigned short* Qb = Rb + (size_t)NREF * KD;                // 4096*256 bf16 = 2MB

  hipLaunchKernelGGL(norm_kernel, dim3(NNW * HN + HN), dim3(256), 0, stream,
                     refs, img, Rb, Qb, out);
  hipLaunchKernelGGL(simmax_kernel, dim3(NCHV * (HW / BMT)), dim3(256), 0, stream,
                     Qb, Rb, out);
}